// Round 1
// baseline (60.164 us; speedup 1.0000x reference)
//
#include <hip/hip_runtime.h>
#include <hip/hip_bf16.h>

typedef __bf16 bf16x8 __attribute__((ext_vector_type(8)));
typedef float f32x4 __attribute__((ext_vector_type(4)));
typedef unsigned short us8 __attribute__((ext_vector_type(8)));

constexpr int NROW = 8192;
constexpr int DCOL = 256;
constexpr int BM = 128;
constexpr int BK = 64;
constexpr int LDP = 72;  // padded LDS row stride (bf16 elems): 144B, 16B-aligned, breaks bank conflicts
constexpr float MARGIN = 0.3f;

// ---------------- normalize rows, write bf16 ----------------
__global__ __launch_bounds__(256) void normalize_kernel(const float* __restrict__ hidden,
                                                        unsigned short* __restrict__ xn) {
    int wid = threadIdx.x >> 6, lane = threadIdx.x & 63;
    int row = (blockIdx.x << 2) + wid;           // 4 rows per block (one per wave)
    const float4* src = reinterpret_cast<const float4*>(hidden + (size_t)row * DCOL);
    float4 v = src[lane];                        // lane covers elems [lane*4, lane*4+4)
    float ss = v.x * v.x + v.y * v.y + v.z * v.z + v.w * v.w;
    #pragma unroll
    for (int off = 32; off; off >>= 1) ss += __shfl_down(ss, off);
    ss = __shfl(ss, 0);
    float inv = 1.0f / fmaxf(sqrtf(ss), 1e-8f);
    __hip_bfloat16 b0 = __float2bfloat16(v.x * inv);
    __hip_bfloat16 b1 = __float2bfloat16(v.y * inv);
    __hip_bfloat16 b2 = __float2bfloat16(v.z * inv);
    __hip_bfloat16 b3 = __float2bfloat16(v.w * inv);
    ushort4 o;
    o.x = *reinterpret_cast<unsigned short*>(&b0);
    o.y = *reinterpret_cast<unsigned short*>(&b1);
    o.z = *reinterpret_cast<unsigned short*>(&b2);
    o.w = *reinterpret_cast<unsigned short*>(&b3);
    reinterpret_cast<ushort4*>(xn + (size_t)row * DCOL)[lane] = o;
}

// ---------------- tiled MFMA Gram + fused pair loss ----------------
__global__ __launch_bounds__(256) void pairloss_kernel(const unsigned short* __restrict__ xn,
                                                       const int* __restrict__ labels,
                                                       float* __restrict__ acc_out) {
    int bi = blockIdx.y, bj = blockIdx.x;
    if (bj < bi) return;                         // upper-triangular tiles only

    __shared__ unsigned short As[BM * LDP];
    __shared__ unsigned short Bs[BM * LDP];
    __shared__ int lblA[BM], lblB[BM];
    __shared__ float wsum[4];

    int tid = threadIdx.x;
    int wid = tid >> 6, lane = tid & 63;
    int wr = wid >> 1, wc = wid & 1;             // 2x2 wave grid, each wave 64x64 out

    int brow = bi * BM, bcol = bj * BM;

    if (tid < BM) lblA[tid] = labels[brow + tid];
    else          lblB[tid - BM] = labels[bcol + tid - BM];

    f32x4 acc[4][4] = {};

    int tr = tid >> 3;          // 0..31
    int tc = (tid & 7) * 8;     // 0..56 (bf16 elems, 16B chunks)

    for (int ks = 0; ks < DCOL; ks += BK) {
        __syncthreads();        // protect LDS tiles from previous iteration's readers
        #pragma unroll
        for (int p = 0; p < 4; ++p) {
            int row = p * 32 + tr;
            us8 a = *reinterpret_cast<const us8*>(xn + (size_t)(brow + row) * DCOL + ks + tc);
            us8 b = *reinterpret_cast<const us8*>(xn + (size_t)(bcol + row) * DCOL + ks + tc);
            *reinterpret_cast<us8*>(&As[row * LDP + tc]) = a;
            *reinterpret_cast<us8*>(&Bs[row * LDP + tc]) = b;
        }
        __syncthreads();
        #pragma unroll
        for (int kk = 0; kk < BK; kk += 32) {
            bf16x8 af[4], bfr[4];
            int ko = kk + ((lane >> 4) << 3);
            #pragma unroll
            for (int m = 0; m < 4; ++m)
                af[m] = *reinterpret_cast<const bf16x8*>(&As[(wr * 64 + m * 16 + (lane & 15)) * LDP + ko]);
            #pragma unroll
            for (int n = 0; n < 4; ++n)
                bfr[n] = *reinterpret_cast<const bf16x8*>(&Bs[(wc * 64 + n * 16 + (lane & 15)) * LDP + ko]);
            #pragma unroll
            for (int m = 0; m < 4; ++m)
                #pragma unroll
                for (int n = 0; n < 4; ++n)
                    acc[m][n] = __builtin_amdgcn_mfma_f32_16x16x32_bf16(af[m], bfr[n], acc[m][n], 0, 0, 0);
        }
    }

    // epilogue: per-pair loss, masked to strict upper triangle
    float local = 0.0f;
    int r0 = wr * 64 + ((lane >> 4) << 2);       // C/D: col=lane&15, row=(lane>>4)*4+reg
    int c0 = wc * 64 + (lane & 15);
    #pragma unroll
    for (int m = 0; m < 4; ++m) {
        #pragma unroll
        for (int n = 0; n < 4; ++n) {
            #pragma unroll
            for (int j = 0; j < 4; ++j) {
                int il = r0 + m * 16 + j;
                int jl = c0 + n * 16;
                int gi = brow + il, gj = bcol + jl;
                float sim = acc[m][n][j];
                float v = (lblA[il] == lblB[jl]) ? (1.0f - sim) : fmaxf(sim - MARGIN, 0.0f);
                local += (gi < gj) ? v : 0.0f;
            }
        }
    }
    #pragma unroll
    for (int off = 32; off; off >>= 1) local += __shfl_down(local, off);
    if (lane == 0) wsum[wid] = local;
    __syncthreads();
    if (tid == 0) atomicAdd(acc_out, wsum[0] + wsum[1] + wsum[2] + wsum[3]);
}

__global__ void finalize_kernel(const float* __restrict__ acc, float* __restrict__ out) {
    constexpr float inv_count = 1.0f / 33550336.0f;   // N*(N-1)/2
    out[0] = acc[0] * inv_count;
}

extern "C" void kernel_launch(void* const* d_in, const int* in_sizes, int n_in,
                              void* d_out, int out_size, void* d_ws, size_t ws_size,
                              hipStream_t stream) {
    const float* hidden = (const float*)d_in[0];
    const int* labels = (const int*)d_in[1];
    float* out = (float*)d_out;

    float* acc = (float*)d_ws;
    unsigned short* xn = (unsigned short*)((char*)d_ws + 256);

    hipMemsetAsync(d_ws, 0, 4, stream);
    normalize_kernel<<<NROW / 4, 256, 0, stream>>>(hidden, xn);
    dim3 grid(NROW / BM, NROW / BM);
    pairloss_kernel<<<grid, 256, 0, stream>>>(xn, labels, acc);
    finalize_kernel<<<1, 1, 0, stream>>>(acc, out);
}

// Round 2
// 48.153 us; speedup vs baseline: 1.2494x; 1.2494x over previous
//
#include <hip/hip_runtime.h>
#include <hip/hip_bf16.h>

typedef __bf16 bf16x8 __attribute__((ext_vector_type(8)));
typedef float f32x4 __attribute__((ext_vector_type(4)));

constexpr int NROW = 8192;
constexpr int DCOL = 256;
constexpr int BM = 128;
constexpr int BK = 64;
constexpr int NT = NROW / BM;              // 64 tile-rows
constexpr int NTILES = NT * (NT + 1) / 2;  // 2080 upper-tri tiles
constexpr float MARGIN = 0.3f;

// async global->LDS, 16B per lane; LDS dest must be wave-uniform base (HW adds lane*16)
__device__ inline void gload16(const unsigned short* g, unsigned short* l) {
    __builtin_amdgcn_global_load_lds(
        (const __attribute__((address_space(1))) void*)g,
        (__attribute__((address_space(3))) void*)l, 16, 0, 0);
}

// ---------------- normalize rows -> bf16, zero the accumulator ----------------
__global__ __launch_bounds__(256) void normalize_kernel(const float* __restrict__ hidden,
                                                        unsigned short* __restrict__ xn,
                                                        float* __restrict__ acc) {
    if (blockIdx.x == 0 && threadIdx.x == 0) acc[0] = 0.0f;
    int wid = threadIdx.x >> 6, lane = threadIdx.x & 63;
    int row = (blockIdx.x << 2) + wid;           // 4 rows per block (one per wave)
    const float4* src = reinterpret_cast<const float4*>(hidden + (size_t)row * DCOL);
    float4 v = src[lane];
    float ss = v.x * v.x + v.y * v.y + v.z * v.z + v.w * v.w;
    #pragma unroll
    for (int off = 32; off; off >>= 1) ss += __shfl_down(ss, off);
    ss = __shfl(ss, 0);
    float inv = 1.0f / fmaxf(sqrtf(ss), 1e-8f);
    __hip_bfloat16 b0 = __float2bfloat16(v.x * inv);
    __hip_bfloat16 b1 = __float2bfloat16(v.y * inv);
    __hip_bfloat16 b2 = __float2bfloat16(v.z * inv);
    __hip_bfloat16 b3 = __float2bfloat16(v.w * inv);
    ushort4 o;
    o.x = *reinterpret_cast<unsigned short*>(&b0);
    o.y = *reinterpret_cast<unsigned short*>(&b1);
    o.z = *reinterpret_cast<unsigned short*>(&b2);
    o.w = *reinterpret_cast<unsigned short*>(&b3);
    reinterpret_cast<ushort4*>(xn + (size_t)row * DCOL)[lane] = o;
}

// ---------------- tiled MFMA Gram + fused pair loss ----------------
__global__ __launch_bounds__(256) void pairloss_kernel(const unsigned short* __restrict__ xn,
                                                       const int* __restrict__ labels,
                                                       float* __restrict__ acc_out) {
    __shared__ unsigned short As[BM * BK];   // linear [128][64], XOR-swizzled contents
    __shared__ unsigned short Bs[BM * BK];
    __shared__ int lblA[BM], lblB[BM];
    __shared__ float wsum[4];

    // unrank linear block id -> upper-triangular (bi, bj), bi <= bj
    int t = blockIdx.x;
    int bi = 0, rem = t;
    while (rem >= NT - bi) { rem -= NT - bi; ++bi; }   // uniform scalar loop, <=64 iters
    int bj = bi + rem;

    int tid = threadIdx.x;
    int wid = tid >> 6, lane = tid & 63;
    int wr = wid >> 1, wc = wid & 1;                   // 2x2 wave grid, 64x64 out each
    int brow = bi * BM, bcol = bj * BM;

    if (tid < BM) lblA[tid] = labels[brow + tid];
    else          lblB[tid - BM] = labels[bcol + tid - BM];

    f32x4 acc[4][4] = {};

    int srow = lane >> 3;        // row within 8-row group this lane feeds
    int sslot = lane & 7;        // 16B slot this lane's data lands in (linear dest)

    for (int ks = 0; ks < DCOL / BK; ++ks) {
        __syncthreads();         // previous iteration's readers done
        #pragma unroll
        for (int q = 0; q < 4; ++q) {
            int rg = (wid * 4 + q) * 8;                 // 8-row group base (wave-uniform)
            int r = rg + srow;
            int c = sslot ^ (r & 7);                    // pre-swizzled global chunk
            const unsigned short* gA = xn + (size_t)(brow + r) * DCOL + ks * BK + c * 8;
            const unsigned short* gB = xn + (size_t)(bcol + r) * DCOL + ks * BK + c * 8;
            gload16(gA, &As[rg * BK]);                  // fills 1KB: 8 rows x 128B
            gload16(gB, &Bs[rg * BK]);
        }
        __syncthreads();         // compiler drains vmcnt before barrier
        #pragma unroll
        for (int kk = 0; kk < 2; ++kk) {
            bf16x8 af[4], bfr[4];
            int cb = kk * 4 + (lane >> 4);              // k-chunk 0..7
            #pragma unroll
            for (int m = 0; m < 4; ++m) {
                int r = wr * 64 + m * 16 + (lane & 15);
                af[m] = *reinterpret_cast<const bf16x8*>(&As[r * BK + ((cb ^ (r & 7)) << 3)]);
            }
            #pragma unroll
            for (int n = 0; n < 4; ++n) {
                int r = wc * 64 + n * 16 + (lane & 15);
                bfr[n] = *reinterpret_cast<const bf16x8*>(&Bs[r * BK + ((cb ^ (r & 7)) << 3)]);
            }
            #pragma unroll
            for (int m = 0; m < 4; ++m)
                #pragma unroll
                for (int n = 0; n < 4; ++n)
                    acc[m][n] = __builtin_amdgcn_mfma_f32_16x16x32_bf16(af[m], bfr[n], acc[m][n], 0, 0, 0);
        }
    }

    // epilogue: per-pair loss, masked to strict upper triangle
    float local = 0.0f;
    int r0 = wr * 64 + ((lane >> 4) << 2);   // C/D: col=lane&15, row=(lane>>4)*4+reg
    int c0 = wc * 64 + (lane & 15);
    #pragma unroll
    for (int m = 0; m < 4; ++m) {
        #pragma unroll
        for (int n = 0; n < 4; ++n) {
            #pragma unroll
            for (int j = 0; j < 4; ++j) {
                int il = r0 + m * 16 + j;
                int jl = c0 + n * 16;
                int gi = brow + il, gj = bcol + jl;
                float sim = acc[m][n][j];
                float v = (lblA[il] == lblB[jl]) ? (1.0f - sim) : fmaxf(sim - MARGIN, 0.0f);
                local += (gi < gj) ? v : 0.0f;
            }
        }
    }
    #pragma unroll
    for (int off = 32; off; off >>= 1) local += __shfl_down(local, off);
    if (lane == 0) wsum[wid] = local;
    __syncthreads();
    if (tid == 0) atomicAdd(acc_out, wsum[0] + wsum[1] + wsum[2] + wsum[3]);
}

__global__ void finalize_kernel(const float* __restrict__ acc, float* __restrict__ out) {
    constexpr float inv_count = 1.0f / 33550336.0f;   // N*(N-1)/2
    out[0] = acc[0] * inv_count;
}

extern "C" void kernel_launch(void* const* d_in, const int* in_sizes, int n_in,
                              void* d_out, int out_size, void* d_ws, size_t ws_size,
                              hipStream_t stream) {
    const float* hidden = (const float*)d_in[0];
    const int* labels = (const int*)d_in[1];
    float* out = (float*)d_out;

    float* acc = (float*)d_ws;
    unsigned short* xn = (unsigned short*)((char*)d_ws + 256);

    normalize_kernel<<<NROW / 4, 256, 0, stream>>>(hidden, xn, acc);
    pairloss_kernel<<<NTILES, 256, 0, stream>>>(xn, labels, acc);
    finalize_kernel<<<1, 1, 0, stream>>>(acc, out);
}